// Round 3
// baseline (615.193 us; speedup 1.0000x reference)
//
#include <hip/hip_runtime.h>
#include <cstdint>
#include <cstddef>

// Problem constants (B=4, T=2048, C=1024, H=16, D=64). I/O dtype: fp32.
#define Bsz   4
#define Tsz   2048
#define Csz   1024
#define Hn    16
#define Dh    64
#define Mrows 8192        // B*T
#define KD    1024        // K dim of both GEMMs (= C)

#define NEG_BIG (-1.0e30f)   // finite mask sentinel: no inf arithmetic anywhere

typedef unsigned short u16;
typedef __bf16  bf16x8 __attribute__((ext_vector_type(8)));
typedef float   f32x4  __attribute__((ext_vector_type(4)));

__device__ __forceinline__ float bf2f(u16 u) {
  union { unsigned int i; float f; } v; v.i = ((unsigned int)u) << 16; return v.f;
}
__device__ __forceinline__ u16 f2bf(float f) {
  union { float f; unsigned int i; } v; v.f = f;
  unsigned int u = v.i;
  return (u16)((u + 0x7fffu + ((u >> 16) & 1u)) >> 16);   // RNE
}

// ---------------------------------------------------------------------------
// Elementwise fp32 -> bf16 convert. n divisible by 1024.
// ---------------------------------------------------------------------------
__global__ __launch_bounds__(256)
void cvt_f32_bf16(const float* __restrict__ in, u16* __restrict__ out, int n4) {
  const int i = blockIdx.x * 256 + threadIdx.x;
  if (i >= n4) return;
  const float4 v = ((const float4*)in)[i];
  ushort4 o;
  o.x = f2bf(v.x); o.y = f2bf(v.y); o.z = f2bf(v.z); o.w = f2bf(v.w);
  ((ushort4*)out)[i] = o;
}

// ---------------------------------------------------------------------------
// Transpose + convert: in fp32 [rows][cols] -> out bf16 [cols][rows].
// grid (cols/64, rows/64), 256 threads.
// ---------------------------------------------------------------------------
__global__ __launch_bounds__(256)
void transpose_f32_bf16(const float* __restrict__ in, u16* __restrict__ out,
                        int rows, int cols) {
  __shared__ u16 tile[64][65];
  const int tc = blockIdx.x * 64, tr = blockIdx.y * 64;
  const int x = threadIdx.x & 63, y0 = threadIdx.x >> 6;
#pragma unroll
  for (int yy = 0; yy < 64; yy += 4) {
    int r = yy + y0;
    tile[r][x] = f2bf(in[(size_t)(tr + r) * cols + tc + x]);
  }
  __syncthreads();
#pragma unroll
  for (int yy = 0; yy < 64; yy += 4) {
    int r = yy + y0;
    out[(size_t)(tc + r) * rows + tr + x] = tile[x][r];
  }
}

// ---------------------------------------------------------------------------
// GEMM C[M,N] = A[M,K] * BT[N,K]^T + bias[N], bf16 in, fp32 acc.
// 128x128 tile, BK=32, 256 threads (2x2 waves, each 64x64 = 4x4 mfma tiles).
// MODE 0: QKV epilogue -> scatter bf16 into q/k/v [B*H][T][D] buffers.
// MODE 1: plain epilogue -> fp32 fout[row*N + col].
// ---------------------------------------------------------------------------
template<int MODE>
__global__ __launch_bounds__(256)
void gemm_bt(const u16* __restrict__ A, const u16* __restrict__ BT,
             const float* __restrict__ bias, u16* __restrict__ o0,
             u16* __restrict__ o1, u16* __restrict__ o2,
             float* __restrict__ fout, int N) {
  __shared__ u16 lsA[128 * 32];
  __shared__ u16 lsB[128 * 32];
  const int tid  = threadIdx.x;
  const int lane = tid & 63;
  const int wid  = tid >> 6;
  const int wm   = wid & 1, wn = wid >> 1;
  const int quad = lane >> 4, l15 = lane & 15;
  const int m0 = blockIdx.y * 128, n0 = blockIdx.x * 128;

  f32x4 acc[4][4];
#pragma unroll
  for (int i = 0; i < 4; ++i)
#pragma unroll
    for (int j = 0; j < 4; ++j) acc[i][j] = (f32x4){0.f, 0.f, 0.f, 0.f};

#if __has_builtin(__builtin_amdgcn_global_load_lds)
  const int srow = lane >> 2, schunk = lane & 3;
  const u16* gA = A  + (size_t)(m0 + wid * 32 + srow) * KD + schunk * 8;
  const u16* gB = BT + (size_t)(n0 + wid * 32 + srow) * KD + schunk * 8;
  u16* lA0 = &lsA[(wid * 32) * 32];
  u16* lB0 = &lsB[(wid * 32) * 32];
#endif

  for (int kk = 0; kk < KD; kk += 32) {
#if __has_builtin(__builtin_amdgcn_global_load_lds)
#pragma unroll
    for (int i = 0; i < 2; ++i) {
      __builtin_amdgcn_global_load_lds(
          (const __attribute__((address_space(1))) void*)(gA + (size_t)i * 16 * KD + kk),
          (__attribute__((address_space(3))) void*)(lA0 + i * 16 * 32), 16, 0, 0);
      __builtin_amdgcn_global_load_lds(
          (const __attribute__((address_space(1))) void*)(gB + (size_t)i * 16 * KD + kk),
          (__attribute__((address_space(3))) void*)(lB0 + i * 16 * 32), 16, 0, 0);
    }
#else
#pragma unroll
    for (int cc = 0; cc < 2; ++cc) {
      int c = tid + cc * 256;
      int row = c >> 2, ch = c & 3;
      *(uint4*)&lsA[row * 32 + ch * 8] =
          *(const uint4*)&A[(size_t)(m0 + row) * KD + kk + ch * 8];
      *(uint4*)&lsB[row * 32 + ch * 8] =
          *(const uint4*)&BT[(size_t)(n0 + row) * KD + kk + ch * 8];
    }
#endif
    __syncthreads();
    bf16x8 af[4], bfv[4];
#pragma unroll
    for (int i = 0; i < 4; ++i)
      af[i] = *(const bf16x8*)&lsA[(wm * 64 + i * 16 + l15) * 32 + quad * 8];
#pragma unroll
    for (int j = 0; j < 4; ++j)
      bfv[j] = *(const bf16x8*)&lsB[(wn * 64 + j * 16 + l15) * 32 + quad * 8];
#pragma unroll
    for (int i = 0; i < 4; ++i)
#pragma unroll
      for (int j = 0; j < 4; ++j)
        acc[i][j] = __builtin_amdgcn_mfma_f32_16x16x32_bf16(af[i], bfv[j],
                                                            acc[i][j], 0, 0, 0);
    __syncthreads();
  }

  // Epilogue. C/D layout: col = lane&15, row = quad*4 + r (verified m89/m91).
#pragma unroll
  for (int i = 0; i < 4; ++i) {
#pragma unroll
    for (int j = 0; j < 4; ++j) {
      const int colb = n0 + wn * 64 + j * 16 + l15;
      const float bv = bias[colb];
#pragma unroll
      for (int r = 0; r < 4; ++r) {
        const int row = m0 + wm * 64 + i * 16 + quad * 4 + r;
        const float val = acc[i][j][r] + bv;
        if (MODE == 0) {
          const int b = row >> 11, t = row & (Tsz - 1);
          const int region = colb >> 10;        // 0:q 1:k 2:v (wave-uniform)
          const int nc = colb & (Csz - 1);
          const int h = nc >> 6, d = nc & 63;
          u16* dst = (region == 0) ? o0 : (region == 1) ? o1 : o2;
          dst[(size_t)(((b << 4) + h) * Tsz + t) * Dh + d] = f2bf(val);
        } else {
          fout[(size_t)row * N + colb] = val;
        }
      }
    }
  }
}

// ---------------------------------------------------------------------------
// Fused causal flash attention.  All-finite arithmetic (fast-math safe).
// q,k,v buffers: [B*H][T][D] bf16. out: [B][T][C] bf16.
// grid (T/64, B*H), 256 threads; wave w owns q rows jq*64+w*16 .. +15.
// ---------------------------------------------------------------------------
__global__ __launch_bounds__(256)
void attn_fused(const u16* __restrict__ qb, const u16* __restrict__ kbuf,
                const u16* __restrict__ vb, u16* __restrict__ outp) {
  __shared__ u16 Kl[64 * 72];      // [key][d], stride 72
  __shared__ u16 Vt[64 * 72];      // [d][key], stride 72
  __shared__ u16 Pl[4][16 * 32];   // per-wave P tile [16 q][32 key]
  const int tid = threadIdx.x, lane = tid & 63, w = tid >> 6;
  const int quad = lane >> 4, l15 = lane & 15;
  const int jq = blockIdx.x, bh = blockIdx.y;
  const int b = bh >> 4, h = bh & 15;
  const size_t base = (size_t)bh * Tsz * Dh;
  const u16* Q  = qb   + base;
  const u16* Kg = kbuf + base;
  const u16* Vg = vb   + base;

  // Q fragments (A-operand layout: m = lane&15, k = quad*8+j), held in regs.
  const int qfrow = jq * 64 + w * 16 + l15;
  const bf16x8 aq0 = *(const bf16x8*)&Q[(size_t)qfrow * Dh + quad * 8];
  const bf16x8 aq1 = *(const bf16x8*)&Q[(size_t)qfrow * Dh + 32 + quad * 8];

  const int qcd = jq * 64 + w * 16 + quad * 4;   // C/D-layout row base (+r)

  f32x4 O[4];
#pragma unroll
  for (int nb = 0; nb < 4; ++nb) O[nb] = (f32x4){0.f, 0.f, 0.f, 0.f};
  float m_i[4], l_i[4];
#pragma unroll
  for (int r = 0; r < 4; ++r) { m_i[r] = NEG_BIG; l_i[r] = 0.f; }

  for (int j = 0; j <= jq; ++j) {
    const int kb = j * 64;
    // Stage K tile [64][64] and V^T tile into LDS (512 x 16B chunks).
#pragma unroll
    for (int cc = 0; cc < 2; ++cc) {
      const int c = tid + cc * 256;
      const int key = c >> 3, off = c & 7;
      *(uint4*)&Kl[key * 72 + off * 8] =
          *(const uint4*)&Kg[(size_t)(kb + key) * Dh + off * 8];
      uint4 vv = *(const uint4*)&Vg[(size_t)(kb + key) * Dh + off * 8];
      const u16* pv = (const u16*)&vv;
#pragma unroll
      for (int e = 0; e < 8; ++e) Vt[(off * 8 + e) * 72 + key] = pv[e];
    }
    __syncthreads();

#pragma unroll
    for (int c = 0; c < 2; ++c) {       // 32-key chunks
      const int k0 = c * 32;
      f32x4 S0 = (f32x4){0.f, 0.f, 0.f, 0.f};
      f32x4 S1 = (f32x4){0.f, 0.f, 0.f, 0.f};
      bf16x8 bk;
      // S = Q K^T : B-operand (kdim=d=quad*8+j, n=key=lane&15) = K[key][d]
      bk = *(const bf16x8*)&Kl[(k0 + l15) * 72 + quad * 8];
      S0 = __builtin_amdgcn_mfma_f32_16x16x32_bf16(aq0, bk, S0, 0, 0, 0);
      bk = *(const bf16x8*)&Kl[(k0 + l15) * 72 + 32 + quad * 8];
      S0 = __builtin_amdgcn_mfma_f32_16x16x32_bf16(aq1, bk, S0, 0, 0, 0);
      bk = *(const bf16x8*)&Kl[(k0 + 16 + l15) * 72 + quad * 8];
      S1 = __builtin_amdgcn_mfma_f32_16x16x32_bf16(aq0, bk, S1, 0, 0, 0);
      bk = *(const bf16x8*)&Kl[(k0 + 16 + l15) * 72 + 32 + quad * 8];
      S1 = __builtin_amdgcn_mfma_f32_16x16x32_bf16(aq1, bk, S1, 0, 0, 0);

      const int kg0 = kb + k0 + l15;
      float alpha[4];
#pragma unroll
      for (int r = 0; r < 4; ++r) {
        const int qg = qcd + r;
        float s0 = (kg0      <= qg) ? S0[r] * 0.125f : NEG_BIG;
        float s1 = (kg0 + 16 <= qg) ? S1[r] * 0.125f : NEG_BIG;
        float mx = fmaxf(s0, s1);
        mx = fmaxf(mx, __shfl_xor(mx, 1, 64));
        mx = fmaxf(mx, __shfl_xor(mx, 2, 64));
        mx = fmaxf(mx, __shfl_xor(mx, 4, 64));
        mx = fmaxf(mx, __shfl_xor(mx, 8, 64));
        const float mn = fmaxf(m_i[r], mx);
        alpha[r] = __expf(m_i[r] - mn);          // finite - finite, always
        const float p0 = __expf(s0 - mn);
        const float p1 = __expf(s1 - mn);
        float rs = p0 + p1;
        rs += __shfl_xor(rs, 1, 64);
        rs += __shfl_xor(rs, 2, 64);
        rs += __shfl_xor(rs, 4, 64);
        rs += __shfl_xor(rs, 8, 64);
        l_i[r] = l_i[r] * alpha[r] + rs;
        m_i[r] = mn;
        Pl[w][(quad * 4 + r) * 32 + l15]      = f2bf(p0);
        Pl[w][(quad * 4 + r) * 32 + 16 + l15] = f2bf(p1);
      }
      __syncthreads();   // P: C-layout write -> A-layout read (cross-lane)
#pragma unroll
      for (int nb = 0; nb < 4; ++nb)
#pragma unroll
        for (int r = 0; r < 4; ++r) O[nb][r] *= alpha[r];
      const bf16x8 ap = *(const bf16x8*)&Pl[w][l15 * 32 + quad * 8];
#pragma unroll
      for (int nb = 0; nb < 4; ++nb) {
        const bf16x8 bv2 =
            *(const bf16x8*)&Vt[(nb * 16 + l15) * 72 + k0 + quad * 8];
        O[nb] = __builtin_amdgcn_mfma_f32_16x16x32_bf16(ap, bv2, O[nb], 0, 0, 0);
      }
    }
    __syncthreads();   // before next tile overwrites K/V LDS
  }

  float inv[4];
#pragma unroll
  for (int r = 0; r < 4; ++r) inv[r] = 1.0f / l_i[r];
#pragma unroll
  for (int nb = 0; nb < 4; ++nb) {
#pragma unroll
    for (int r = 0; r < 4; ++r) {
      const int t = qcd + r;
      outp[(size_t)(b * Tsz + t) * Csz + h * Dh + nb * 16 + l15] =
          f2bf(O[nb][r] * inv[r]);
    }
  }
}

// ---------------------------------------------------------------------------
extern "C" void kernel_launch(void* const* d_in, const int* in_sizes, int n_in,
                              void* d_out, int out_size, void* d_ws, size_t ws_size,
                              hipStream_t stream) {
  const float* x      = (const float*)d_in[0];   // [B,T,C] fp32
  const float* W_attn = (const float*)d_in[1];   // [C,3C]  fp32
  const float* b_attn = (const float*)d_in[2];   // [3C]    fp32
  const float* W_proj = (const float*)d_in[3];   // [C,C]   fp32
  const float* b_proj = (const float*)d_in[4];   // [C]     fp32
  float* out = (float*)d_out;                    // [B,T,C] fp32

  u16* ws   = (u16*)d_ws;
  u16* xbf  = ws;                                // [B,T,C] bf16
  u16* qbuf = xbf  + (size_t)Mrows * Csz;        // [B*H][T][D]
  u16* kbuf = qbuf + (size_t)Mrows * Csz;
  u16* vbuf = kbuf + (size_t)Mrows * Csz;
  u16* aout = vbuf + (size_t)Mrows * Csz;        // [B,T,C] bf16
  u16* WTa  = aout + (size_t)Mrows * Csz;        // [3C][C] bf16
  u16* WTp  = WTa  + (size_t)Csz * 3 * Csz;      // [C][C]  bf16

  cvt_f32_bf16<<<(Mrows * Csz / 4 + 255) / 256, 256, 0, stream>>>(
      x, xbf, Mrows * Csz / 4);
  transpose_f32_bf16<<<dim3(3 * Csz / 64, Csz / 64), 256, 0, stream>>>(
      W_attn, WTa, Csz, 3 * Csz);
  transpose_f32_bf16<<<dim3(Csz / 64, Csz / 64), 256, 0, stream>>>(
      W_proj, WTp, Csz, Csz);
  gemm_bt<0><<<dim3(3 * Csz / 128, Mrows / 128), 256, 0, stream>>>(
      xbf, WTa, b_attn, qbuf, kbuf, vbuf, nullptr, 3 * Csz);
  attn_fused<<<dim3(Tsz / 64, Bsz * Hn), 256, 0, stream>>>(
      qbuf, kbuf, vbuf, aout);
  gemm_bt<1><<<dim3(Csz / 128, Mrows / 128), 256, 0, stream>>>(
      aout, WTp, b_proj, nullptr, nullptr, nullptr, out, Csz);
}

// Round 4
// 300.813 us; speedup vs baseline: 2.0451x; 2.0451x over previous
//
#include <hip/hip_runtime.h>
#include <cstdint>
#include <cstddef>

// Problem constants (B=4, T=2048, C=1024, H=16, D=64). I/O dtype: fp32.
#define Bsz   4
#define Tsz   2048
#define Csz   1024
#define Hn    16
#define Dh    64
#define Mrows 8192        // B*T
#define KD    1024        // K dim of both GEMMs (= C)

#define NEG_BIG (-1.0e30f)   // finite mask sentinel: no inf arithmetic anywhere

typedef unsigned short u16;
typedef __bf16  bf16x8 __attribute__((ext_vector_type(8)));
typedef float   f32x4  __attribute__((ext_vector_type(4)));

__device__ __forceinline__ float bf2f(u16 u) {
  union { unsigned int i; float f; } v; v.i = ((unsigned int)u) << 16; return v.f;
}
__device__ __forceinline__ u16 f2bf(float f) {
  union { float f; unsigned int i; } v; v.f = f;
  unsigned int u = v.i;
  return (u16)((u + 0x7fffu + ((u >> 16) & 1u)) >> 16);   // RNE
}

// ---------------------------------------------------------------------------
// Elementwise fp32 -> bf16 convert.
// ---------------------------------------------------------------------------
__global__ __launch_bounds__(256)
void cvt_f32_bf16(const float* __restrict__ in, u16* __restrict__ out, int n4) {
  const int i = blockIdx.x * 256 + threadIdx.x;
  if (i >= n4) return;
  const float4 v = ((const float4*)in)[i];
  ushort4 o;
  o.x = f2bf(v.x); o.y = f2bf(v.y); o.z = f2bf(v.z); o.w = f2bf(v.w);
  ((ushort4*)out)[i] = o;
}

// ---------------------------------------------------------------------------
// Transpose + convert: in fp32 [rows][cols] -> out bf16 [cols][rows].
// ---------------------------------------------------------------------------
__global__ __launch_bounds__(256)
void transpose_f32_bf16(const float* __restrict__ in, u16* __restrict__ out,
                        int rows, int cols) {
  __shared__ u16 tile[64][65];
  const int tc = blockIdx.x * 64, tr = blockIdx.y * 64;
  const int x = threadIdx.x & 63, y0 = threadIdx.x >> 6;
#pragma unroll
  for (int yy = 0; yy < 64; yy += 4) {
    int r = yy + y0;
    tile[r][x] = f2bf(in[(size_t)(tr + r) * cols + tc + x]);
  }
  __syncthreads();
#pragma unroll
  for (int yy = 0; yy < 64; yy += 4) {
    int r = yy + y0;
    out[(size_t)(tc + r) * rows + tr + x] = tile[x][r];
  }
}

// ---------------------------------------------------------------------------
// GEMM C[M,N] = A[M,K] * BT[N,K]^T + bias[N], bf16 in, fp32 acc.
// 128x128 tile, BK=32, 256 threads (2x2 waves, each 64x64 = 4x4 mfma tiles).
// MODE 0: QKV epilogue -> scatter bf16 into q/k/v [B*H][T][D] buffers.
// MODE 1: plain epilogue -> fp32 fout[row*N + col].
// ---------------------------------------------------------------------------
template<int MODE>
__global__ __launch_bounds__(256)
void gemm_bt(const u16* __restrict__ A, const u16* __restrict__ BT,
             const float* __restrict__ bias, u16* __restrict__ o0,
             u16* __restrict__ o1, u16* __restrict__ o2,
             float* __restrict__ fout, int N) {
  __shared__ u16 lsA[128 * 32];
  __shared__ u16 lsB[128 * 32];
  const int tid  = threadIdx.x;
  const int lane = tid & 63;
  const int wid  = tid >> 6;
  const int wm   = wid & 1, wn = wid >> 1;
  const int quad = lane >> 4, l15 = lane & 15;
  const int m0 = blockIdx.y * 128, n0 = blockIdx.x * 128;

  f32x4 acc[4][4];
#pragma unroll
  for (int i = 0; i < 4; ++i)
#pragma unroll
    for (int j = 0; j < 4; ++j) acc[i][j] = (f32x4){0.f, 0.f, 0.f, 0.f};

#if __has_builtin(__builtin_amdgcn_global_load_lds)
  const int srow = lane >> 2, schunk = lane & 3;
  const u16* gA = A  + (size_t)(m0 + wid * 32 + srow) * KD + schunk * 8;
  const u16* gB = BT + (size_t)(n0 + wid * 32 + srow) * KD + schunk * 8;
  u16* lA0 = &lsA[(wid * 32) * 32];
  u16* lB0 = &lsB[(wid * 32) * 32];
#endif

  for (int kk = 0; kk < KD; kk += 32) {
#if __has_builtin(__builtin_amdgcn_global_load_lds)
#pragma unroll
    for (int i = 0; i < 2; ++i) {
      __builtin_amdgcn_global_load_lds(
          (const __attribute__((address_space(1))) void*)(gA + (size_t)i * 16 * KD + kk),
          (__attribute__((address_space(3))) void*)(lA0 + i * 16 * 32), 16, 0, 0);
      __builtin_amdgcn_global_load_lds(
          (const __attribute__((address_space(1))) void*)(gB + (size_t)i * 16 * KD + kk),
          (__attribute__((address_space(3))) void*)(lB0 + i * 16 * 32), 16, 0, 0);
    }
#else
#pragma unroll
    for (int cc = 0; cc < 2; ++cc) {
      int c = tid + cc * 256;
      int row = c >> 2, ch = c & 3;
      *(uint4*)&lsA[row * 32 + ch * 8] =
          *(const uint4*)&A[(size_t)(m0 + row) * KD + kk + ch * 8];
      *(uint4*)&lsB[row * 32 + ch * 8] =
          *(const uint4*)&BT[(size_t)(n0 + row) * KD + kk + ch * 8];
    }
#endif
    __syncthreads();
    bf16x8 af[4], bfv[4];
#pragma unroll
    for (int i = 0; i < 4; ++i)
      af[i] = *(const bf16x8*)&lsA[(wm * 64 + i * 16 + l15) * 32 + quad * 8];
#pragma unroll
    for (int j = 0; j < 4; ++j)
      bfv[j] = *(const bf16x8*)&lsB[(wn * 64 + j * 16 + l15) * 32 + quad * 8];
#pragma unroll
    for (int i = 0; i < 4; ++i)
#pragma unroll
      for (int j = 0; j < 4; ++j)
        acc[i][j] = __builtin_amdgcn_mfma_f32_16x16x32_bf16(af[i], bfv[j],
                                                            acc[i][j], 0, 0, 0);
    __syncthreads();
  }

  // Epilogue. C/D layout: col = lane&15, row = quad*4 + r (verified m89/m91).
#pragma unroll
  for (int i = 0; i < 4; ++i) {
#pragma unroll
    for (int j = 0; j < 4; ++j) {
      const int colb = n0 + wn * 64 + j * 16 + l15;
      const float bv = bias[colb];
#pragma unroll
      for (int r = 0; r < 4; ++r) {
        const int row = m0 + wm * 64 + i * 16 + quad * 4 + r;
        const float val = acc[i][j][r] + bv;
        if (MODE == 0) {
          const int b = row >> 11, t = row & (Tsz - 1);
          const int region = colb >> 10;        // 0:q 1:k 2:v (wave-uniform)
          const int nc = colb & (Csz - 1);
          const int h = nc >> 6, d = nc & 63;
          u16* dst = (region == 0) ? o0 : (region == 1) ? o1 : o2;
          dst[(size_t)(((b << 4) + h) * Tsz + t) * Dh + d] = f2bf(val);
        } else {
          fout[(size_t)row * N + colb] = val;
        }
      }
    }
  }
}

// ---------------------------------------------------------------------------
// Fused causal flash attention, V2: transposed-score formulation.
//   S^T = mfma(K_frag, Q_frag)  -> C-layout col = q = lane&15, row = key.
//   Each lane owns ONE q-column: softmax reductions = in-register over 8
//   scores + 2 shuffles (xor 16, 32). P^T stays in registers and feeds the
//   PV MFMA (O^T = V^T * P^T) as the B operand under key-permutation
//   pi(quad*8+j) shared by both operands (bijection on [0,32) -> valid).
//   alpha and 1/l_i apply per-lane with no cross-lane traffic; no P LDS
//   round-trip; 2 barriers per 64-key tile. Only the diagonal tile masks.
// q,k,v: [B*H][T][D] bf16. out (aout): [B][T][C] bf16.
// grid (bh=64, jqslot=32); jq = 31 - blockIdx.y so heavy blocks launch first.
// ---------------------------------------------------------------------------
__global__ __launch_bounds__(256)
void attn_fused(const u16* __restrict__ qb, const u16* __restrict__ kbuf,
                const u16* __restrict__ vb, u16* __restrict__ outp) {
  __shared__ u16 Kl[64 * 72];      // [key][d], pad 72
  __shared__ u16 Vt[64 * 76];      // [d][key], pad 76 (spreads transpose-write banks)
  const int tid = threadIdx.x, lane = tid & 63, w = tid >> 6;
  const int quad = lane >> 4, l15 = lane & 15;
  const int bh = blockIdx.x;
  const int jq = 31 - blockIdx.y;            // heavy first -> no straggler tail
  const int b = bh >> 4, h = bh & 15;
  const size_t base = (size_t)bh * Tsz * Dh;
  const u16* Q  = qb   + base;
  const u16* Kg = kbuf + base;
  const u16* Vg = vb   + base;

  // Q fragment (B-operand of S^T): lane holds Q[q=l15][d=quad*8+j], d-halves.
  const int qrow = jq * 64 + w * 16 + l15;   // this lane's q (global row)
  const bf16x8 bq0 = *(const bf16x8*)&Q[(size_t)qrow * Dh + quad * 8];
  const bf16x8 bq1 = *(const bf16x8*)&Q[(size_t)qrow * Dh + 32 + quad * 8];

  f32x4 O[4];      // O^T: col q = l15, row d = nb*16 + quad*4 + r
#pragma unroll
  for (int nb = 0; nb < 4; ++nb) O[nb] = (f32x4){0.f, 0.f, 0.f, 0.f};
  float m_i = NEG_BIG, l_i = 0.f;            // state for q = l15 (replicated x4)

  for (int j = 0; j <= jq; ++j) {
    const int kb = j * 64;
    // Stage K [key][d] (b128) and V^T [d][key] into LDS.
#pragma unroll
    for (int cc = 0; cc < 2; ++cc) {
      const int c = tid + cc * 256;
      const int key = c >> 3, off = c & 7;
      *(uint4*)&Kl[key * 72 + off * 8] =
          *(const uint4*)&Kg[(size_t)(kb + key) * Dh + off * 8];
      uint4 vv = *(const uint4*)&Vg[(size_t)(kb + key) * Dh + off * 8];
      const u16* pv = (const u16*)&vv;
#pragma unroll
      for (int e = 0; e < 8; ++e) Vt[(off * 8 + e) * 76 + key] = pv[e];
    }
    __syncthreads();

    const bool diag = (j == jq);
    const int cmax = diag ? ((w * 16 + 15) >> 5) + 1 : 2;  // skip fully-masked
    for (int c = 0; c < cmax; ++c) {
      const int k0 = c * 32;
      // S^T: two 16-key tiles. A = K fragment (m=key=l15, k=d=quad*8+j).
      f32x4 S0 = (f32x4){0.f, 0.f, 0.f, 0.f};
      f32x4 S1 = (f32x4){0.f, 0.f, 0.f, 0.f};
      bf16x8 ak;
      ak = *(const bf16x8*)&Kl[(k0 + l15) * 72 + quad * 8];
      S0 = __builtin_amdgcn_mfma_f32_16x16x32_bf16(ak, bq0, S0, 0, 0, 0);
      ak = *(const bf16x8*)&Kl[(k0 + l15) * 72 + 32 + quad * 8];
      S0 = __builtin_amdgcn_mfma_f32_16x16x32_bf16(ak, bq1, S0, 0, 0, 0);
      ak = *(const bf16x8*)&Kl[(k0 + 16 + l15) * 72 + quad * 8];
      S1 = __builtin_amdgcn_mfma_f32_16x16x32_bf16(ak, bq0, S1, 0, 0, 0);
      ak = *(const bf16x8*)&Kl[(k0 + 16 + l15) * 72 + 32 + quad * 8];
      S1 = __builtin_amdgcn_mfma_f32_16x16x32_bf16(ak, bq1, S1, 0, 0, 0);

      // Scores for q=qrow, keys kb+k0+quad*4+r (S0) and +16 (S1).
      const int key0 = kb + k0 + quad * 4;
      float s0[4], s1[4];
      if (diag) {
#pragma unroll
        for (int r = 0; r < 4; ++r) {
          s0[r] = (key0 + r      <= qrow) ? S0[r] * 0.125f : NEG_BIG;
          s1[r] = (key0 + 16 + r <= qrow) ? S1[r] * 0.125f : NEG_BIG;
        }
      } else {
#pragma unroll
        for (int r = 0; r < 4; ++r) {
          s0[r] = S0[r] * 0.125f;
          s1[r] = S1[r] * 0.125f;
        }
      }
      float mx = s0[0];
#pragma unroll
      for (int r = 1; r < 4; ++r) mx = fmaxf(mx, s0[r]);
#pragma unroll
      for (int r = 0; r < 4; ++r) mx = fmaxf(mx, s1[r]);
      mx = fmaxf(mx, __shfl_xor(mx, 16, 64));
      mx = fmaxf(mx, __shfl_xor(mx, 32, 64));
      const float mn = fmaxf(m_i, mx);
      const float alpha = __expf(m_i - mn);
      float p0[4], p1[4], rs = 0.f;
#pragma unroll
      for (int r = 0; r < 4; ++r) {
        p0[r] = __expf(s0[r] - mn);
        p1[r] = __expf(s1[r] - mn);
        rs += p0[r] + p1[r];
      }
      rs += __shfl_xor(rs, 16, 64);
      rs += __shfl_xor(rs, 32, 64);
      l_i = l_i * alpha + rs;
      m_i = mn;

      // P^T B-fragment: k=quad*8+j -> key pi = k0+quad*4+j (j<4), +16 (j>=4).
      union { u16 u[8]; bf16x8 v; } pb;
#pragma unroll
      for (int r = 0; r < 4; ++r) {
        pb.u[r]     = f2bf(p0[r]);
        pb.u[4 + r] = f2bf(p1[r]);
      }
#pragma unroll
      for (int nb = 0; nb < 4; ++nb)
#pragma unroll
        for (int r = 0; r < 4; ++r) O[nb][r] *= alpha;
      // PV: O^T += V^T * P^T. A = Vt fragment (m=d=l15, same pi key order).
#pragma unroll
      for (int nb = 0; nb < 4; ++nb) {
        union { uint2 d[2]; bf16x8 v; } av;
        av.d[0] = *(const uint2*)&Vt[(nb * 16 + l15) * 76 + k0 + quad * 4];
        av.d[1] = *(const uint2*)&Vt[(nb * 16 + l15) * 76 + k0 + 16 + quad * 4];
        O[nb] = __builtin_amdgcn_mfma_f32_16x16x32_bf16(av.v, pb.v, O[nb], 0, 0, 0);
      }
    }
    __syncthreads();   // before next tile overwrites K/V LDS
  }

  // Final: O^T col q = l15 -> per-lane 1/l_i, rows d = nb*16+quad*4+r.
  const float inv = 1.0f / l_i;
#pragma unroll
  for (int nb = 0; nb < 4; ++nb) {
    ushort4 ov;
    ov.x = f2bf(O[nb][0] * inv);
    ov.y = f2bf(O[nb][1] * inv);
    ov.z = f2bf(O[nb][2] * inv);
    ov.w = f2bf(O[nb][3] * inv);
    *(ushort4*)&outp[(size_t)(b * Tsz + qrow) * Csz + h * Dh + nb * 16 + quad * 4] = ov;
  }
}

// ---------------------------------------------------------------------------
extern "C" void kernel_launch(void* const* d_in, const int* in_sizes, int n_in,
                              void* d_out, int out_size, void* d_ws, size_t ws_size,
                              hipStream_t stream) {
  const float* x      = (const float*)d_in[0];   // [B,T,C] fp32
  const float* W_attn = (const float*)d_in[1];   // [C,3C]  fp32
  const float* b_attn = (const float*)d_in[2];   // [3C]    fp32
  const float* W_proj = (const float*)d_in[3];   // [C,C]   fp32
  const float* b_proj = (const float*)d_in[4];   // [C]     fp32
  float* out = (float*)d_out;                    // [B,T,C] fp32

  u16* ws   = (u16*)d_ws;
  u16* xbf  = ws;                                // [B,T,C] bf16
  u16* qbuf = xbf  + (size_t)Mrows * Csz;        // [B*H][T][D]
  u16* kbuf = qbuf + (size_t)Mrows * Csz;
  u16* vbuf = kbuf + (size_t)Mrows * Csz;
  u16* aout = vbuf + (size_t)Mrows * Csz;        // [B,T,C] bf16
  u16* WTa  = aout + (size_t)Mrows * Csz;        // [3C][C] bf16
  u16* WTp  = WTa  + (size_t)Csz * 3 * Csz;      // [C][C]  bf16

  cvt_f32_bf16<<<(Mrows * Csz / 4 + 255) / 256, 256, 0, stream>>>(
      x, xbf, Mrows * Csz / 4);
  transpose_f32_bf16<<<dim3(3 * Csz / 64, Csz / 64), 256, 0, stream>>>(
      W_attn, WTa, Csz, 3 * Csz);
  transpose_f32_bf16<<<dim3(Csz / 64, Csz / 64), 256, 0, stream>>>(
      W_proj, WTp, Csz, Csz);
  gemm_bt<0><<<dim3(3 * Csz / 128, Mrows / 128), 256, 0, stream>>>(
      xbf, WTa, b_attn, qbuf, kbuf, vbuf, nullptr, 3 * Csz);
  attn_fused<<<dim3(Bsz * Hn, Tsz / 64), 256, 0, stream>>>(
      qbuf, kbuf, vbuf, aout);
  gemm_bt<1><<<dim3(Csz / 128, Mrows / 128), 256, 0, stream>>>(
      aout, WTp, b_proj, nullptr, nullptr, nullptr, out, Csz);
}

// Round 5
// 273.358 us; speedup vs baseline: 2.2505x; 1.1004x over previous
//
#include <hip/hip_runtime.h>
#include <cstdint>
#include <cstddef>

// Problem constants (B=4, T=2048, C=1024, H=16, D=64). I/O dtype: fp32.
#define Bsz   4
#define Tsz   2048
#define Csz   1024
#define Hn    16
#define Dh    64
#define Mrows 8192        // B*T
#define KD    1024        // K dim of both GEMMs (= C)

#define NEG_BIG (-1.0e30f)   // finite mask sentinel: no inf arithmetic anywhere
#define SCL2 0.18033688011112042f   // (1/sqrt(64)) * log2(e): folded into exp2

typedef unsigned short u16;
typedef __bf16  bf16x8 __attribute__((ext_vector_type(8)));
typedef __bf16  bf16x2 __attribute__((ext_vector_type(2)));
typedef float   f32x4  __attribute__((ext_vector_type(4)));

__device__ __forceinline__ u16 f2bf(float f) {
  union { float f; unsigned int i; } v; v.f = f;
  unsigned int u = v.i;
  return (u16)((u + 0x7fffu + ((u >> 16) & 1u)) >> 16);   // RNE
}
// Pack two f32 -> two bf16 in one uint (low = a, high = b).
__device__ __forceinline__ unsigned int pack2bf(float a, float b) {
#if __has_builtin(__builtin_amdgcn_cvt_pk_bf16_f32)
  union { bf16x2 h; unsigned int u; } cv;
  cv.h = __builtin_amdgcn_cvt_pk_bf16_f32(a, b);
  return cv.u;
#else
  return (unsigned int)f2bf(a) | ((unsigned int)f2bf(b) << 16);
#endif
}
__device__ __forceinline__ float fast_exp2(float x) {
#if __has_builtin(__builtin_amdgcn_exp2f)
  return __builtin_amdgcn_exp2f(x);
#else
  return exp2f(x);
#endif
}

// ---------------------------------------------------------------------------
// Elementwise fp32 -> bf16 convert.
// ---------------------------------------------------------------------------
__global__ __launch_bounds__(256)
void cvt_f32_bf16(const float* __restrict__ in, u16* __restrict__ out, int n4) {
  const int i = blockIdx.x * 256 + threadIdx.x;
  if (i >= n4) return;
  const float4 v = ((const float4*)in)[i];
  uint2 o;
  o.x = pack2bf(v.x, v.y);
  o.y = pack2bf(v.z, v.w);
  ((uint2*)out)[i] = o;
}

// ---------------------------------------------------------------------------
// Transpose + convert: in fp32 [rows][cols] -> out bf16 [cols][rows].
// ---------------------------------------------------------------------------
__global__ __launch_bounds__(256)
void transpose_f32_bf16(const float* __restrict__ in, u16* __restrict__ out,
                        int rows, int cols) {
  __shared__ u16 tile[64][65];
  const int tc = blockIdx.x * 64, tr = blockIdx.y * 64;
  const int x = threadIdx.x & 63, y0 = threadIdx.x >> 6;
#pragma unroll
  for (int yy = 0; yy < 64; yy += 4) {
    int r = yy + y0;
    tile[r][x] = f2bf(in[(size_t)(tr + r) * cols + tc + x]);
  }
  __syncthreads();
#pragma unroll
  for (int yy = 0; yy < 64; yy += 4) {
    int r = yy + y0;
    out[(size_t)(tc + r) * rows + tr + x] = tile[x][r];
  }
}

// ---------------------------------------------------------------------------
// GEMM C[M,N] = A[M,K] * BT[N,K]^T + bias[N], bf16 in, fp32 acc.
// 128x128 tile, BK=32, 256 threads (2x2 waves, each 64x64 = 4x4 mfma tiles).
// MODE 0: QKV epilogue -> q/k scatter [bh][t][d]; V scatter TRANSPOSED
//         [bh][d][t] (packed 8B stores) so attn can stage V^T with b128 copies.
// MODE 1: plain epilogue -> fp32 fout[row*N + col].
// ---------------------------------------------------------------------------
template<int MODE>
__global__ __launch_bounds__(256)
void gemm_bt(const u16* __restrict__ A, const u16* __restrict__ BT,
             const float* __restrict__ bias, u16* __restrict__ o0,
             u16* __restrict__ o1, u16* __restrict__ o2,
             float* __restrict__ fout, int N) {
  __shared__ u16 lsA[128 * 32];
  __shared__ u16 lsB[128 * 32];
  const int tid  = threadIdx.x;
  const int lane = tid & 63;
  const int wid  = tid >> 6;
  const int wm   = wid & 1, wn = wid >> 1;
  const int quad = lane >> 4, l15 = lane & 15;
  const int m0 = blockIdx.y * 128, n0 = blockIdx.x * 128;

  f32x4 acc[4][4];
#pragma unroll
  for (int i = 0; i < 4; ++i)
#pragma unroll
    for (int j = 0; j < 4; ++j) acc[i][j] = (f32x4){0.f, 0.f, 0.f, 0.f};

#if __has_builtin(__builtin_amdgcn_global_load_lds)
  const int srow = lane >> 2, schunk = lane & 3;
  const u16* gA = A  + (size_t)(m0 + wid * 32 + srow) * KD + schunk * 8;
  const u16* gB = BT + (size_t)(n0 + wid * 32 + srow) * KD + schunk * 8;
  u16* lA0 = &lsA[(wid * 32) * 32];
  u16* lB0 = &lsB[(wid * 32) * 32];
#endif

  for (int kk = 0; kk < KD; kk += 32) {
#if __has_builtin(__builtin_amdgcn_global_load_lds)
#pragma unroll
    for (int i = 0; i < 2; ++i) {
      __builtin_amdgcn_global_load_lds(
          (const __attribute__((address_space(1))) void*)(gA + (size_t)i * 16 * KD + kk),
          (__attribute__((address_space(3))) void*)(lA0 + i * 16 * 32), 16, 0, 0);
      __builtin_amdgcn_global_load_lds(
          (const __attribute__((address_space(1))) void*)(gB + (size_t)i * 16 * KD + kk),
          (__attribute__((address_space(3))) void*)(lB0 + i * 16 * 32), 16, 0, 0);
    }
#else
#pragma unroll
    for (int cc = 0; cc < 2; ++cc) {
      int c = tid + cc * 256;
      int row = c >> 2, ch = c & 3;
      *(uint4*)&lsA[row * 32 + ch * 8] =
          *(const uint4*)&A[(size_t)(m0 + row) * KD + kk + ch * 8];
      *(uint4*)&lsB[row * 32 + ch * 8] =
          *(const uint4*)&BT[(size_t)(n0 + row) * KD + kk + ch * 8];
    }
#endif
    __syncthreads();
    bf16x8 af[4], bfv[4];
#pragma unroll
    for (int i = 0; i < 4; ++i)
      af[i] = *(const bf16x8*)&lsA[(wm * 64 + i * 16 + l15) * 32 + quad * 8];
#pragma unroll
    for (int j = 0; j < 4; ++j)
      bfv[j] = *(const bf16x8*)&lsB[(wn * 64 + j * 16 + l15) * 32 + quad * 8];
#pragma unroll
    for (int i = 0; i < 4; ++i)
#pragma unroll
      for (int j = 0; j < 4; ++j)
        acc[i][j] = __builtin_amdgcn_mfma_f32_16x16x32_bf16(af[i], bfv[j],
                                                            acc[i][j], 0, 0, 0);
    __syncthreads();
  }

  // Epilogue. C/D layout: col = lane&15, row = quad*4 + r (verified m89/m91).
#pragma unroll
  for (int i = 0; i < 4; ++i) {
#pragma unroll
    for (int j = 0; j < 4; ++j) {
      const int colb = n0 + wn * 64 + j * 16 + l15;
      const float bv = bias[colb];
      float vals[4];
#pragma unroll
      for (int r = 0; r < 4; ++r) vals[r] = acc[i][j][r] + bv;
      const int row0 = m0 + wm * 64 + i * 16 + quad * 4;
      if (MODE == 0) {
        const int b = row0 >> 11, t0 = row0 & (Tsz - 1);
        const int region = colb >> 10;        // 0:q 1:k 2:v (block-uniform)
        const int nc = colb & (Csz - 1);
        const int h = nc >> 6, d = nc & 63;
        if (region == 2) {
          // V transposed: [bh][d][t]; 4 consecutive t -> one 8B store.
          uint2 st;
          st.x = pack2bf(vals[0], vals[1]);
          st.y = pack2bf(vals[2], vals[3]);
          *(uint2*)&o2[((size_t)((b << 4) + h) * Dh + d) * Tsz + t0] = st;
        } else {
          u16* dst = (region == 0) ? o0 : o1;
#pragma unroll
          for (int r = 0; r < 4; ++r)
            dst[(size_t)(((b << 4) + h) * Tsz + t0 + r) * Dh + d] = f2bf(vals[r]);
        }
      } else {
#pragma unroll
        for (int r = 0; r < 4; ++r)
          fout[(size_t)(row0 + r) * N + colb] = vals[r];
      }
    }
  }
}

// ---------------------------------------------------------------------------
// Fused causal flash attention, V3: transposed scores + 64-key softmax batch.
//   S^T = mfma(K_frag, Q_frag): lane owns q = lane&15; keys = quad*4+r+16t.
//   One softmax update per 64-key tile (16 scores/lane in regs, 2 shuffles).
//   V arrives pre-transposed [bh][d][t] (from gemm<0>) -> b128 LDS staging.
//   Scale 1/sqrt(D) folded into exp2 argument. Diagonal tiles skip fully-
//   masked 16-key sub-tiles (t <= w). 2 barriers per tile.
// grid (bh=64, jqslot=32); jq = 31 - blockIdx.y so heavy blocks launch first.
// ---------------------------------------------------------------------------
__global__ __launch_bounds__(256)
void attn_fused(const u16* __restrict__ qb, const u16* __restrict__ kbuf,
                const u16* __restrict__ vT, u16* __restrict__ outp) {
  __shared__ u16 Kl[64 * 72];      // [key][d], pad 72
  __shared__ u16 Vt[64 * 72];      // [d][key], pad 72 (staged from vT rows)
  const int tid = threadIdx.x, lane = tid & 63, w = tid >> 6;
  const int quad = lane >> 4, l15 = lane & 15;
  const int bh = blockIdx.x;
  const int jq = 31 - blockIdx.y;            // heavy first -> no straggler tail
  const int b = bh >> 4, h = bh & 15;
  const u16* Q   = qb   + (size_t)bh * Tsz * Dh;
  const u16* Kg  = kbuf + (size_t)bh * Tsz * Dh;
  const u16* VTg = vT   + (size_t)bh * Dh * Tsz;

  // Q fragment (B-operand of S^T): lane holds Q[q=l15][d=quad*8+j], d-halves.
  const int qrow = jq * 64 + w * 16 + l15;   // this lane's q (global row)
  const bf16x8 bq0 = *(const bf16x8*)&Q[(size_t)qrow * Dh + quad * 8];
  const bf16x8 bq1 = *(const bf16x8*)&Q[(size_t)qrow * Dh + 32 + quad * 8];

  f32x4 O[4];      // O^T: col q = l15, row d = nb*16 + quad*4 + r
#pragma unroll
  for (int nb = 0; nb < 4; ++nb) O[nb] = (f32x4){0.f, 0.f, 0.f, 0.f};
  float m_i = NEG_BIG, l_i = 0.f;            // state for q = l15 (replicated x4)

  for (int j = 0; j <= jq; ++j) {
    const int kb = j * 64;
    // Stage K [key][d] and V^T [d][key] via pure b128 copies.
#pragma unroll
    for (int cc = 0; cc < 2; ++cc) {
      const int c = tid + cc * 256;
      const int rr = c >> 3, off = c & 7;
      *(uint4*)&Kl[rr * 72 + off * 8] =
          *(const uint4*)&Kg[(size_t)(kb + rr) * Dh + off * 8];
      *(uint4*)&Vt[rr * 72 + off * 8] =
          *(const uint4*)&VTg[(size_t)rr * Tsz + kb + off * 8];
    }
    __syncthreads();

    const bool diag = (j == jq);
    const int tmax = diag ? (w + 1) : 4;     // 16-key sub-tiles with any work

    // S^T: A = K fragment (m=key=16t+l15, k=d=quad*8+jj), B = Q fragment.
    f32x4 S[4];
#pragma unroll
    for (int t = 0; t < 4; ++t) S[t] = (f32x4){0.f, 0.f, 0.f, 0.f};
#pragma unroll
    for (int t = 0; t < 4; ++t) {
      if (t < tmax) {
        bf16x8 ak = *(const bf16x8*)&Kl[(t * 16 + l15) * 72 + quad * 8];
        S[t] = __builtin_amdgcn_mfma_f32_16x16x32_bf16(ak, bq0, S[t], 0, 0, 0);
        ak = *(const bf16x8*)&Kl[(t * 16 + l15) * 72 + 32 + quad * 8];
        S[t] = __builtin_amdgcn_mfma_f32_16x16x32_bf16(ak, bq1, S[t], 0, 0, 0);
      }
    }

    // Scores (raw domain; 1/sqrt(D) folded into exp2 scale).
    float s[4][4];
#pragma unroll
    for (int t = 0; t < 4; ++t)
#pragma unroll
      for (int r = 0; r < 4; ++r) s[t][r] = NEG_BIG;
    if (diag) {
#pragma unroll
      for (int t = 0; t < 4; ++t) {
        if (t < tmax) {
          const int key0 = kb + t * 16 + quad * 4;
#pragma unroll
          for (int r = 0; r < 4; ++r)
            s[t][r] = (key0 + r <= qrow) ? S[t][r] : NEG_BIG;
        }
      }
    } else {
#pragma unroll
      for (int t = 0; t < 4; ++t)
#pragma unroll
        for (int r = 0; r < 4; ++r) s[t][r] = S[t][r];
    }

    // One online-softmax update over 16 scores/lane.
    float mx = s[0][0];
#pragma unroll
    for (int t = 0; t < 4; ++t)
#pragma unroll
      for (int r = 0; r < 4; ++r) mx = fmaxf(mx, s[t][r]);
    mx = fmaxf(mx, __shfl_xor(mx, 16, 64));
    mx = fmaxf(mx, __shfl_xor(mx, 32, 64));
    const float mn = fmaxf(m_i, mx);
    const float alpha = fast_exp2((m_i - mn) * SCL2);
    float p[4][4], rs = 0.f;
#pragma unroll
    for (int t = 0; t < 4; ++t)
#pragma unroll
      for (int r = 0; r < 4; ++r) {
        p[t][r] = fast_exp2((s[t][r] - mn) * SCL2);
        rs += p[t][r];
      }
    rs += __shfl_xor(rs, 16, 64);
    rs += __shfl_xor(rs, 32, 64);
    l_i = l_i * alpha + rs;
    m_i = mn;

#pragma unroll
    for (int nb = 0; nb < 4; ++nb)
#pragma unroll
      for (int r = 0; r < 4; ++r) O[nb][r] *= alpha;

    // PV chunk 0 (keys 0..31 = tiles 0,1): B-frag key pi(quad*8+jj).
    union PB { unsigned int u32[4]; bf16x8 v; } pb;
    pb.u32[0] = pack2bf(p[0][0], p[0][1]);
    pb.u32[1] = pack2bf(p[0][2], p[0][3]);
    pb.u32[2] = pack2bf(p[1][0], p[1][1]);
    pb.u32[3] = pack2bf(p[1][2], p[1][3]);
#pragma unroll
    for (int nb = 0; nb < 4; ++nb) {
      union { uint2 d[2]; bf16x8 v; } av;
      av.d[0] = *(const uint2*)&Vt[(nb * 16 + l15) * 72 + quad * 4];
      av.d[1] = *(const uint2*)&Vt[(nb * 16 + l15) * 72 + 16 + quad * 4];
      O[nb] = __builtin_amdgcn_mfma_f32_16x16x32_bf16(av.v, pb.v, O[nb], 0, 0, 0);
    }
    if (tmax > 2) {   // PV chunk 1 (keys 32..63 = tiles 2,3)
      pb.u32[0] = pack2bf(p[2][0], p[2][1]);
      pb.u32[1] = pack2bf(p[2][2], p[2][3]);
      pb.u32[2] = pack2bf(p[3][0], p[3][1]);
      pb.u32[3] = pack2bf(p[3][2], p[3][3]);
#pragma unroll
      for (int nb = 0; nb < 4; ++nb) {
        union { uint2 d[2]; bf16x8 v; } av;
        av.d[0] = *(const uint2*)&Vt[(nb * 16 + l15) * 72 + 32 + quad * 4];
        av.d[1] = *(const uint2*)&Vt[(nb * 16 + l15) * 72 + 48 + quad * 4];
        O[nb] = __builtin_amdgcn_mfma_f32_16x16x32_bf16(av.v, pb.v, O[nb], 0, 0, 0);
      }
    }
    __syncthreads();   // before next tile overwrites K/V LDS
  }

  // Final: O^T col q = l15 -> per-lane 1/l_i, rows d = nb*16+quad*4+r.
  const float inv = 1.0f / l_i;
#pragma unroll
  for (int nb = 0; nb < 4; ++nb) {
    uint2 st;
    st.x = pack2bf(O[nb][0] * inv, O[nb][1] * inv);
    st.y = pack2bf(O[nb][2] * inv, O[nb][3] * inv);
    *(uint2*)&outp[(size_t)(b * Tsz + qrow) * Csz + h * Dh + nb * 16 + quad * 4] = st;
  }
}

// ---------------------------------------------------------------------------
extern "C" void kernel_launch(void* const* d_in, const int* in_sizes, int n_in,
                              void* d_out, int out_size, void* d_ws, size_t ws_size,
                              hipStream_t stream) {
  const float* x      = (const float*)d_in[0];   // [B,T,C] fp32
  const float* W_attn = (const float*)d_in[1];   // [C,3C]  fp32
  const float* b_attn = (const float*)d_in[2];   // [3C]    fp32
  const float* W_proj = (const float*)d_in[3];   // [C,C]   fp32
  const float* b_proj = (const float*)d_in[4];   // [C]     fp32
  float* out = (float*)d_out;                    // [B,T,C] fp32

  u16* ws   = (u16*)d_ws;
  u16* xbf  = ws;                                // [B,T,C] bf16
  u16* qbuf = xbf  + (size_t)Mrows * Csz;        // [bh][t][d]
  u16* kbuf = qbuf + (size_t)Mrows * Csz;        // [bh][t][d]
  u16* vbuf = kbuf + (size_t)Mrows * Csz;        // [bh][d][t]  (transposed!)
  u16* aout = vbuf + (size_t)Mrows * Csz;        // [B,T,C] bf16
  u16* WTa  = aout + (size_t)Mrows * Csz;        // [3C][C] bf16
  u16* WTp  = WTa  + (size_t)Csz * 3 * Csz;      // [C][C]  bf16

  cvt_f32_bf16<<<(Mrows * Csz / 4 + 255) / 256, 256, 0, stream>>>(
      x, xbf, Mrows * Csz / 4);
  transpose_f32_bf16<<<dim3(3 * Csz / 64, Csz / 64), 256, 0, stream>>>(
      W_attn, WTa, Csz, 3 * Csz);
  transpose_f32_bf16<<<dim3(Csz / 64, Csz / 64), 256, 0, stream>>>(
      W_proj, WTp, Csz, Csz);
  gemm_bt<0><<<dim3(3 * Csz / 128, Mrows / 128), 256, 0, stream>>>(
      xbf, WTa, b_attn, qbuf, kbuf, vbuf, nullptr, 3 * Csz);
  attn_fused<<<dim3(Bsz * Hn, Tsz / 64), 256, 0, stream>>>(
      qbuf, kbuf, vbuf, aout);
  gemm_bt<1><<<dim3(Csz / 128, Mrows / 128), 256, 0, stream>>>(
      aout, WTp, b_proj, nullptr, nullptr, nullptr, out, Csz);
}